// Round 1
// baseline (115.271 us; speedup 1.0000x reference)
//
#include <hip/hip_runtime.h>
#include <math.h>

#define DEV __device__ __forceinline__

// ---------------------------------------------------------------------------
// Complex helpers (float2 = {re, im})
// ---------------------------------------------------------------------------
DEV float2 shfl_xor_f2(float2 v, int m) {
    return make_float2(__shfl_xor(v.x, m, 64), __shfl_xor(v.y, m, 64));
}

// ---------------------------------------------------------------------------
// 8-qubit score circuit: state distributed across the wave.
// Amplitude index i = lane*4 + r  (r = bits 0..1, lane = bits 2..7).
// Wire w lives at index-bit (7-w):  wires 0..5 -> lane bits 5..0,
//                                   wires 6,7 -> register bits 1,0.
// ---------------------------------------------------------------------------

// Partner values for amplitudes flipped by `mask` (8-bit amplitude-index mask).
DEV void sc_partner(const float2 s[4], float2 p[4], int mask) {
    const int rm = mask & 3;       // register-bit part
    const int lm = mask >> 2;      // lane-bit part
#pragma unroll
    for (int r = 0; r < 4; r++) p[r] = s[r ^ rm];
    if (lm) {
#pragma unroll
        for (int r = 0; r < 4; r++) p[r] = shfl_xor_f2(p[r], lm);
    }
}

// RZ(t) on wire w. cs = (cos(t/2), sin(t/2)).  U = diag(e^{-it/2}, e^{+it/2}).
DEV void sc_rz(float2 s[4], int lane, int w, float2 cs) {
#pragma unroll
    for (int r = 0; r < 4; r++) {
        const int bit = ((lane * 4 + r) >> (7 - w)) & 1;
        const float sn = bit ? cs.y : -cs.y;
        const float2 a = s[r];
        s[r] = make_float2(a.x * cs.x - a.y * sn, a.x * sn + a.y * cs.x);
    }
}

// RX(t) on wire w:  a' = c*a + (-i s)*partner
DEV void sc_rx(float2 s[4], int lane, int w, float2 cs) {
    float2 p[4];
    sc_partner(s, p, 1 << (7 - w));
    const float c = cs.x, sn = cs.y;
#pragma unroll
    for (int r = 0; r < 4; r++) {
        const float2 a = s[r], b = p[r];
        s[r] = make_float2(c * a.x + sn * b.y, c * a.y - sn * b.x);
    }
}

// CRX(t) control cw, target tw
DEV void sc_crx(float2 s[4], int lane, int cw, int tw, float2 cs) {
    float2 p[4];
    sc_partner(s, p, 1 << (7 - tw));
    const float c = cs.x, sn = cs.y;
#pragma unroll
    for (int r = 0; r < 4; r++) {
        const int ctrl = ((lane * 4 + r) >> (7 - cw)) & 1;
        const float2 a = s[r], b = p[r];
        const float2 rx = make_float2(c * a.x + sn * b.y, c * a.y - sn * b.x);
        s[r] = ctrl ? rx : a;
    }
}

// IsingXX(t) on wires (w1, w2): a' = c*a + (-i s)*a[flip both bits]
DEV void sc_ixx(float2 s[4], int w1, int w2, float2 cs) {
    float2 p[4];
    sc_partner(s, p, (1 << (7 - w1)) | (1 << (7 - w2)));
    const float c = cs.x, sn = cs.y;
#pragma unroll
    for (int r = 0; r < 4; r++) {
        const float2 a = s[r], b = p[r];
        s[r] = make_float2(c * a.x + sn * b.y, c * a.y - sn * b.x);
    }
}

// CNOT control cw, target tw
DEV void sc_cnot(float2 s[4], int lane, int cw, int tw) {
    float2 p[4];
    sc_partner(s, p, 1 << (7 - tw));
#pragma unroll
    for (int r = 0; r < 4; r++) {
        const int ctrl = ((lane * 4 + r) >> (7 - cw)) & 1;
        s[r] = ctrl ? p[r] : s[r];
    }
}

// rot layer: RZ,RX,RZ on wires offset..offset+3, params cs[3i..3i+2]
DEV void sc_rot_layer(float2 s[4], int lane, const float2* cs, int offset) {
#pragma unroll
    for (int i = 0; i < 4; i++) {
        sc_rz(s, lane, offset + i, cs[3 * i]);
        sc_rx(s, lane, offset + i, cs[3 * i + 1]);
        sc_rz(s, lane, offset + i, cs[3 * i + 2]);
    }
}

DEV void sc_two_ring(float2 s[4], int lane, const float2* rot, const float2* crx,
                     int offset) {
    sc_rot_layer(s, lane, rot, offset);
#pragma unroll
    for (int i = 0; i < 4; i++)
        sc_crx(s, lane, offset + i, offset + ((i + 1) & 3), crx[i]);
#pragma unroll
    for (int i = 0; i < 4; i++)
        sc_ixx(s, offset + i, offset + ((i + 1) & 3), crx[4 + i]);
    sc_rot_layer(s, lane, rot + 12, offset);
}

// ---------------------------------------------------------------------------
// LDS layout for precomputed (cos(t/2), sin(t/2)) of all weight angles
// ---------------------------------------------------------------------------
enum {
    QROT = 0,    // 24
    QCRX = 24,   // 8
    KROT = 32,   // 24
    KCRX = 56,   // 8
    VROT = 64,   // 24
    VCRX = 88,   // 8
    CROT = 96,   // 12
    CCRX = 108,  // 8
    CCRX2 = 116, // 8
    NANG = 124
};

__global__ __launch_bounds__(256) void qa_kernel(
    const float* __restrict__ x_text, const float* __restrict__ x_image,
    const float* __restrict__ W_text, const float* __restrict__ b_text,
    const float* __restrict__ W_image, const float* __restrict__ b_image,
    const float* __restrict__ wq_rot, const float* __restrict__ wq_crx,
    const float* __restrict__ wk_rot, const float* __restrict__ wk_crx,
    const float* __restrict__ wv_rot, const float* __restrict__ wv_crx,
    const float* __restrict__ wc_rot, const float* __restrict__ wc_crx,
    const float* __restrict__ wc_crx2, const float* __restrict__ gates,
    float* __restrict__ out, int B)
{
    __shared__ float2 csh[NANG];
    const int tid = threadIdx.x;
    if (tid < NANG) {
        float t;
        if (tid < 24)       t = wq_rot[tid];
        else if (tid < 32)  t = wq_crx[tid - 24];
        else if (tid < 56)  t = wk_rot[tid - 32];
        else if (tid < 64)  t = wk_crx[tid - 56];
        else if (tid < 88)  t = wv_rot[tid - 64];
        else if (tid < 96)  t = wv_crx[tid - 88];
        else if (tid < 108) t = wc_rot[tid - 96];
        else if (tid < 116) t = wc_crx[tid - 108];
        else                t = wc_crx2[tid - 116];
        float s_, c_;
        sincosf(0.5f * t, &s_, &c_);
        csh[tid] = make_float2(c_, s_);
    }
    __syncthreads();

    const int lane = tid & 63;
    const int b = blockIdx.x * 4 + (tid >> 6);
    if (b >= B) return;

    // ---- projections: xq = x_text @ W_text^T + b_text ; xk likewise --------
    const float* xt = x_text + (size_t)b * 96;
    const float* xi = x_image + (size_t)b * 96;
    float acc[8];
#pragma unroll
    for (int j = 0; j < 8; j++) acc[j] = 0.f;
    {
        const float vt = xt[lane], vi = xi[lane];
#pragma unroll
        for (int j = 0; j < 4; j++) {
            acc[j]     += vt * W_text[j * 96 + lane];
            acc[4 + j] += vi * W_image[j * 96 + lane];
        }
        if (lane < 32) {
            const float vt2 = xt[64 + lane], vi2 = xi[64 + lane];
#pragma unroll
            for (int j = 0; j < 4; j++) {
                acc[j]     += vt2 * W_text[j * 96 + 64 + lane];
                acc[4 + j] += vi2 * W_image[j * 96 + 64 + lane];
            }
        }
    }
#pragma unroll
    for (int j = 0; j < 8; j++) {
#pragma unroll
        for (int m = 32; m >= 1; m >>= 1) acc[j] += __shfl_xor(acc[j], m, 64);
    }
    float xq[4], xk[4];
#pragma unroll
    for (int j = 0; j < 4; j++) {
        xq[j] = acc[j] + b_text[j];
        xk[j] = acc[4 + j] + b_image[j];
    }

    // ---- 8-qubit score circuit --------------------------------------------
    float2 s[4];
#pragma unroll
    for (int r = 0; r < 4; r++) s[r] = make_float2(0.f, 0.f);
    s[0].x = (lane == 0) ? 1.f : 0.f;

#pragma unroll
    for (int i = 0; i < 4; i++) {  // AngleEmbedding xq on wires 0..3
        float s_, c_;
        __sincosf(0.5f * xq[i], &s_, &c_);
        sc_rx(s, lane, i, make_float2(c_, s_));
    }
    sc_two_ring(s, lane, csh + QROT, csh + QCRX, 0);
#pragma unroll
    for (int i = 0; i < 4; i++) {  // AngleEmbedding xk on wires 4..7
        float s_, c_;
        __sincosf(0.5f * xk[i], &s_, &c_);
        sc_rx(s, lane, 4 + i, make_float2(c_, s_));
    }
    sc_two_ring(s, lane, csh + KROT, csh + KCRX, 4);
#pragma unroll
    for (int i = 0; i < 4; i++) {  // cross CRX both directions
        sc_crx(s, lane, i, i + 4, csh[CCRX + i]);
        sc_crx(s, lane, i + 4, i, csh[CCRX + i + 4]);
    }
#pragma unroll
    for (int i = 0; i < 4; i++)
        sc_crx(s, lane, i, ((i + 1) & 3) + 4, csh[CCRX2 + i]);
#pragma unroll
    for (int i = 0; i < 4; i++)
        sc_crx(s, lane, i + 4, (i + 1) & 3, csh[CCRX2 + i + 4]);
#pragma unroll
    for (int i = 0; i < 4; i++) {  // CNOT both directions
        sc_cnot(s, lane, i, i + 4);
        sc_cnot(s, lane, i + 4, i);
    }
    sc_rot_layer(s, lane, csh + CROT, 0);

    // ---- expectations Z,X on wires 0..3 -----------------------------------
    float zx[8];
#pragma unroll
    for (int w = 0; w < 4; w++) {
        const float sign = ((lane >> (5 - w)) & 1) ? -1.f : 1.f;
        float tz = 0.f;
#pragma unroll
        for (int r = 0; r < 4; r++) tz += s[r].x * s[r].x + s[r].y * s[r].y;
        zx[w] = sign * tz;
        float2 p[4];
        sc_partner(s, p, 1 << (7 - w));
        float tx = 0.f;
#pragma unroll
        for (int r = 0; r < 4; r++) tx += s[r].x * p[r].x + s[r].y * p[r].y;
        zx[4 + w] = tx;
    }
#pragma unroll
    for (int j = 0; j < 8; j++) {
#pragma unroll
        for (int m = 32; m >= 1; m >>= 1) zx[j] += __shfl_xor(zx[j], m, 64);
    }
    float amp[4];
#pragma unroll
    for (int i = 0; i < 4; i++)
        amp[i] = sqrtf(zx[i] * zx[i] + zx[4 + i] * zx[4 + i]);

    // ---- 4-qubit value circuit: 1 amplitude per lane, replicated x4 -------
    // amplitude index = lane & 15; wire w at bit (3-w)
    const int l4 = lane & 15;
    float2 v = make_float2((l4 == 0) ? 1.f : 0.f, 0.f);

    auto vrz = [&](int w, float2 cs_) {
        const int bit = (l4 >> (3 - w)) & 1;
        const float sn = bit ? cs_.y : -cs_.y;
        v = make_float2(v.x * cs_.x - v.y * sn, v.x * sn + v.y * cs_.x);
    };
    auto vrx = [&](int w, float2 cs_) {
        const float2 p = shfl_xor_f2(v, 1 << (3 - w));
        v = make_float2(cs_.x * v.x + cs_.y * p.y, cs_.x * v.y - cs_.y * p.x);
    };
    auto vcrx = [&](int cw, int tw, float2 cs_) {
        const float2 p = shfl_xor_f2(v, 1 << (3 - tw));
        const float2 rx =
            make_float2(cs_.x * v.x + cs_.y * p.y, cs_.x * v.y - cs_.y * p.x);
        const int ctrl = (l4 >> (3 - cw)) & 1;
        v = ctrl ? rx : v;
    };
    auto vixx = [&](int w1, int w2, float2 cs_) {
        const float2 p = shfl_xor_f2(v, (1 << (3 - w1)) | (1 << (3 - w2)));
        v = make_float2(cs_.x * v.x + cs_.y * p.y, cs_.x * v.y - cs_.y * p.x);
    };
    auto vcnot = [&](int cw, int tw) {
        const float2 p = shfl_xor_f2(v, 1 << (3 - tw));
        const int ctrl = (l4 >> (3 - cw)) & 1;
        v = ctrl ? p : v;
    };

#pragma unroll
    for (int i = 0; i < 4; i++) {  // AngleEmbedding xk (xv = xk)
        float s_, c_;
        __sincosf(0.5f * xk[i], &s_, &c_);
        vrx(i, make_float2(c_, s_));
    }
    // two_ring(wv_rot, wv_crx, 0)
#pragma unroll
    for (int i = 0; i < 4; i++) {
        vrz(i, csh[VROT + 3 * i]);
        vrx(i, csh[VROT + 3 * i + 1]);
        vrz(i, csh[VROT + 3 * i + 2]);
    }
#pragma unroll
    for (int i = 0; i < 4; i++) vcrx(i, (i + 1) & 3, csh[VCRX + i]);
#pragma unroll
    for (int i = 0; i < 4; i++) vixx(i, (i + 1) & 3, csh[VCRX + 4 + i]);
#pragma unroll
    for (int i = 0; i < 4; i++) {
        vrz(i, csh[VROT + 12 + 3 * i]);
        vrx(i, csh[VROT + 12 + 3 * i + 1]);
        vrz(i, csh[VROT + 12 + 3 * i + 2]);
    }
#pragma unroll
    for (int i = 0; i < 4; i++) {  // RX(tanh(amp)*gates)
        const float ang = tanhf(amp[i]) * gates[i];
        float s_, c_;
        __sincosf(0.5f * ang, &s_, &c_);
        vrx(i, make_float2(c_, s_));
    }
#pragma unroll
    for (int i = 0; i < 4; i++) vcnot(i, (i + 1) & 3);

    float oz[4], ox[4];
#pragma unroll
    for (int w = 0; w < 4; w++) {
        const float sign = ((l4 >> (3 - w)) & 1) ? -1.f : 1.f;
        oz[w] = sign * (v.x * v.x + v.y * v.y);
        const float2 p = shfl_xor_f2(v, 1 << (3 - w));
        ox[w] = v.x * p.x + v.y * p.y;
    }
#pragma unroll
    for (int w = 0; w < 4; w++) {
#pragma unroll
        for (int m = 8; m >= 1; m >>= 1) {
            oz[w] += __shfl_xor(oz[w], m, 64);
            ox[w] += __shfl_xor(ox[w], m, 64);
        }
    }
    if (lane == 0) {
        float4* o = (float4*)(out + (size_t)b * 8);
        o[0] = make_float4(oz[0], oz[1], oz[2], oz[3]);
        o[1] = make_float4(ox[0], ox[1], ox[2], ox[3]);
    }
}

extern "C" void kernel_launch(void* const* d_in, const int* in_sizes, int n_in,
                              void* d_out, int out_size, void* d_ws, size_t ws_size,
                              hipStream_t stream) {
    (void)n_in; (void)out_size; (void)d_ws; (void)ws_size;
    const int B = in_sizes[0] / 96;
    const dim3 grid((B + 3) / 4), block(256);
    hipLaunchKernelGGL(qa_kernel, grid, block, 0, stream,
                       (const float*)d_in[0], (const float*)d_in[1],
                       (const float*)d_in[2], (const float*)d_in[3],
                       (const float*)d_in[4], (const float*)d_in[5],
                       (const float*)d_in[6], (const float*)d_in[7],
                       (const float*)d_in[8], (const float*)d_in[9],
                       (const float*)d_in[10], (const float*)d_in[11],
                       (const float*)d_in[12], (const float*)d_in[13],
                       (const float*)d_in[14], (const float*)d_in[15],
                       (float*)d_out, B);
}

// Round 2
// 102.456 us; speedup vs baseline: 1.1251x; 1.1251x over previous
//
#include <hip/hip_runtime.h>
#include <math.h>

#define DEV __device__ __forceinline__

// ---------------------------------------------------------------------------
// Cross-lane xor within 16-lane groups. Masks 1,2,3 -> DPP quad_perm,
// mask 8 -> DPP row_ror:8 (row = 16 lanes on gfx9-lineage), else ds_swizzle
// (bit-mode, xor<=15 stays within 32-lane groups).
// ---------------------------------------------------------------------------
template<int M>
DEV float lxor(float x) {
    const int i = __builtin_bit_cast(int, x);
    int r;
    if constexpr (M == 1)      r = __builtin_amdgcn_update_dpp(i, i, 0xB1, 0xF, 0xF, false);
    else if constexpr (M == 2) r = __builtin_amdgcn_update_dpp(i, i, 0x4E, 0xF, 0xF, false);
    else if constexpr (M == 3) r = __builtin_amdgcn_update_dpp(i, i, 0x1B, 0xF, 0xF, false);
    else if constexpr (M == 8) r = __builtin_amdgcn_update_dpp(i, i, 0x128, 0xF, 0xF, false);
    else                       r = __builtin_amdgcn_ds_swizzle(i, (M << 10) | 0x1F);
    return __builtin_bit_cast(float, r);
}
template<int M> DEV float2 lxor2(float2 v) {
    return make_float2(lxor<M>(v.x), lxor<M>(v.y));
}
DEV float red16(float x) {
    x += lxor<8>(x); x += lxor<4>(x); x += lxor<2>(x); x += lxor<1>(x);
    return x;
}

// ---------------------------------------------------------------------------
// 8-qubit state: 16 float2 per lane (register bits = wires 0..3, bit 3-w),
// 16 lanes per element (lane bits = wires 4..7, bit 7-w). 4 elements/wave.
// General SU(2) gate: [[u00, u01], [-conj(u01), conj(u00)]].
// ---------------------------------------------------------------------------
template<int RM>
DEV void rgate(float2 (&s)[16], float2 u00, float2 u01) {
#pragma unroll
    for (int r = 0; r < 16; r++) {
        if (r & RM) continue;
        const int r1 = r | RM;
        const float2 a = s[r], b = s[r1];
        s[r]  = make_float2(u00.x*a.x - u00.y*a.y + u01.x*b.x - u01.y*b.y,
                            u00.x*a.y + u00.y*a.x + u01.x*b.y + u01.y*b.x);
        s[r1] = make_float2(u00.x*b.x + u00.y*b.y - u01.x*a.x - u01.y*a.y,
                            u00.x*b.y - u00.y*b.x - u01.x*a.y + u01.y*a.x);
    }
}
template<int RM>
DEV void rgate4(float2 (&s)[16], float4 g) {
    rgate<RM>(s, make_float2(g.x, g.y), make_float2(g.z, g.w));
}

template<int LM>
DEV void lgate(float2 (&s)[16], int l4, float2 u00, float2 u01) {
    const bool hi = (l4 & LM) != 0;
    const float e00x = u00.x, e00y = hi ? -u00.y : u00.y;
    const float e01x = hi ? -u01.x : u01.x, e01y = u01.y;
#pragma unroll
    for (int r = 0; r < 16; r++) {
        const float2 p = lxor2<LM>(s[r]);
        const float2 a = s[r];
        s[r] = make_float2(e00x*a.x - e00y*a.y + e01x*p.x - e01y*p.y,
                           e00x*a.y + e00y*a.x + e01x*p.y + e01y*p.x);
    }
}
template<int LM>
DEV void lgate4(float2 (&s)[16], int l4, float4 g) {
    lgate<LM>(s, l4, make_float2(g.x, g.y), make_float2(g.z, g.w));
}

// CRX variants. cs = (cos(t/2), sin(t/2)); RX pair: a' = c*a + sn*(b.y,-b.x)
template<int CM, int TM>
DEV void crx_rr(float2 (&s)[16], float2 cs) {
#pragma unroll
    for (int r = 0; r < 16; r++) {
        if (!(r & CM) || (r & TM)) continue;
        const int r1 = r | TM;
        const float2 a = s[r], b = s[r1];
        s[r]  = make_float2(cs.x*a.x + cs.y*b.y, cs.x*a.y - cs.y*b.x);
        s[r1] = make_float2(cs.x*b.x + cs.y*a.y, cs.x*b.y - cs.y*a.x);
    }
}
template<int CL, int TM>
DEV void crx_lr(float2 (&s)[16], int l4, float2 cs) {
    const bool hi = (l4 & CL) != 0;
    const float c = hi ? cs.x : 1.f, sn = hi ? cs.y : 0.f;
#pragma unroll
    for (int r = 0; r < 16; r++) {
        if (r & TM) continue;
        const int r1 = r | TM;
        const float2 a = s[r], b = s[r1];
        s[r]  = make_float2(c*a.x + sn*b.y, c*a.y - sn*b.x);
        s[r1] = make_float2(c*b.x + sn*a.y, c*b.y - sn*a.x);
    }
}
template<int CM, int LM>
DEV void crx_rl(float2 (&s)[16], float2 cs) {
#pragma unroll
    for (int r = 0; r < 16; r++) {
        if (!(r & CM)) continue;
        const float2 p = lxor2<LM>(s[r]);
        const float2 a = s[r];
        s[r] = make_float2(cs.x*a.x + cs.y*p.y, cs.x*a.y - cs.y*p.x);
    }
}
template<int CL, int LM>
DEV void crx_ll(float2 (&s)[16], int l4, float2 cs) {
    const bool hi = (l4 & CL) != 0;
    const float c = hi ? cs.x : 1.f, sn = hi ? cs.y : 0.f;
#pragma unroll
    for (int r = 0; r < 16; r++) {
        const float2 p = lxor2<LM>(s[r]);
        const float2 a = s[r];
        s[r] = make_float2(c*a.x + sn*p.y, c*a.y - sn*p.x);
    }
}

// IsingXX
template<int M2>
DEV void ixx_rr(float2 (&s)[16], float2 cs) {
    constexpr int HB = (M2 & 8) ? 8 : ((M2 & 4) ? 4 : 2);
#pragma unroll
    for (int r = 0; r < 16; r++) {
        if (r & HB) continue;
        const int r1 = r ^ M2;
        const float2 a = s[r], b = s[r1];
        s[r]  = make_float2(cs.x*a.x + cs.y*b.y, cs.x*a.y - cs.y*b.x);
        s[r1] = make_float2(cs.x*b.x + cs.y*a.y, cs.x*b.y - cs.y*a.x);
    }
}
template<int LM2>
DEV void ixx_ll(float2 (&s)[16], float2 cs) {
#pragma unroll
    for (int r = 0; r < 16; r++) {
        const float2 p = lxor2<LM2>(s[r]);
        const float2 a = s[r];
        s[r] = make_float2(cs.x*a.x + cs.y*p.y, cs.x*a.y - cs.y*p.x);
    }
}

// CNOT
template<int CM, int LM>
DEV void cnot_rl(float2 (&s)[16]) {
#pragma unroll
    for (int r = 0; r < 16; r++) {
        if (r & CM) s[r] = lxor2<LM>(s[r]);
    }
}
template<int CL, int TM>
DEV void cnot_lr(float2 (&s)[16], int l4) {
    const bool hi = (l4 & CL) != 0;
#pragma unroll
    for (int r = 0; r < 16; r++) {
        if (r & TM) continue;
        const int r1 = r | TM;
        const float2 a = s[r], b = s[r1];
        s[r]  = hi ? b : a;
        s[r1] = hi ? a : b;
    }
}

template<int RM>
DEV void measZX(const float2 (&s)[16], float& z, float& x) {
    float zz = 0.f, xx = 0.f;
#pragma unroll
    for (int r = 0; r < 16; r++) {
        const float n2 = s[r].x*s[r].x + s[r].y*s[r].y;
        zz += (r & RM) ? -n2 : n2;
        xx += s[r].x*s[r ^ RM].x + s[r].y*s[r ^ RM].y;
    }
    z = zz; x = xx;
}

// Fuse rot-layer SU(2) g with preceding RX(ang): U' = M * RX(ang)
DEV void fuse_rx(float4 g, float ang, float2& u00, float2& u01) {
    float s_, c_;
    __sincosf(0.5f * ang, &s_, &c_);
    u00 = make_float2(g.x*c_ + g.w*s_, g.y*c_ - g.z*s_);
    u01 = make_float2(g.y*s_ + g.z*c_, -g.x*s_ + g.w*c_);
}

// ---- 4-qubit value circuit: 1 amp/lane across the 16-lane group -----------
template<int LM>
DEV void vgate(float2& v, int l4, float2 u00, float2 u01) {
    const bool hi = (l4 & LM) != 0;
    const float e00x = u00.x, e00y = hi ? -u00.y : u00.y;
    const float e01x = hi ? -u01.x : u01.x, e01y = u01.y;
    const float2 p = lxor2<LM>(v);
    v = make_float2(e00x*v.x - e00y*v.y + e01x*p.x - e01y*p.y,
                    e00x*v.y + e00y*v.x + e01x*p.y + e01y*p.x);
}
template<int LM>
DEV void vgate4(float2& v, int l4, float4 g) {
    vgate<LM>(v, l4, make_float2(g.x, g.y), make_float2(g.z, g.w));
}
template<int CL, int LM>
DEV void vcrx(float2& v, int l4, float2 cs) {
    const bool hi = (l4 & CL) != 0;
    const float c = hi ? cs.x : 1.f, sn = hi ? cs.y : 0.f;
    const float2 p = lxor2<LM>(v);
    v = make_float2(c*v.x + sn*p.y, c*v.y - sn*p.x);
}
template<int LM2>
DEV void vixx(float2& v, float2 cs) {
    const float2 p = lxor2<LM2>(v);
    v = make_float2(cs.x*v.x + cs.y*p.y, cs.x*v.y - cs.y*p.x);
}
template<int LM>
DEV void vrx(float2& v, float c, float sn) {
    const float2 p = lxor2<LM>(v);
    v = make_float2(c*v.x + sn*p.y, c*v.y - sn*p.x);
}
template<int CL, int LM>
DEV void vcnot(float2& v, int l4) {
    const float2 p = lxor2<LM>(v);
    const bool hi = (l4 & CL) != 0;
    v = hi ? p : v;
}

// ---------------------------------------------------------------------------
__global__ __launch_bounds__(256, 1) void qa_kernel(
    const float* __restrict__ x_text, const float* __restrict__ x_image,
    const float* __restrict__ W_text, const float* __restrict__ b_text,
    const float* __restrict__ W_image, const float* __restrict__ b_image,
    const float* __restrict__ wq_rot, const float* __restrict__ wq_crx,
    const float* __restrict__ wk_rot, const float* __restrict__ wk_crx,
    const float* __restrict__ wv_rot, const float* __restrict__ wv_crx,
    const float* __restrict__ wc_rot, const float* __restrict__ wc_crx,
    const float* __restrict__ wc_crx2, const float* __restrict__ gates,
    float* __restrict__ out, int B)
{
    // sG: fused SU(2) per rot-layer wire: 0-3 qL1, 4-7 qL2, 8-11 kL1,
    // 12-15 kL2, 16-19 final, 20-23 vL1, 24-27 vL2.  (u00re,u00im,u01re,u01im)
    __shared__ float4 sG[28];
    // sCS: (cos(t/2),sin(t/2)): 0-7 wq_crx, 8-15 wk_crx, 16-23 wc_crx,
    // 24-31 wc_crx2, 32-39 wv_crx.
    __shared__ float2 sCS[40];
    __shared__ float4 sWT[192];  // transposed W rows: [0..95]=W_text, [96..191]=W_image

    const int tid = threadIdx.x;
    if (tid < 192) {
        const float* W = (tid < 96) ? W_text : W_image;
        const int idx = (tid < 96) ? tid : tid - 96;
        sWT[tid] = make_float4(W[idx], W[96 + idx], W[192 + idx], W[288 + idx]);
    }
    if (tid < 28) {
        const float* srcs[7] = {wq_rot, wq_rot + 12, wk_rot, wk_rot + 12,
                                wc_rot, wv_rot, wv_rot + 12};
        const float* p = srcs[tid >> 2] + 3 * (tid & 3);
        const float a = p[0], bb = p[1], c = p[2];
        float sh, ch, sd, cd, sb, cb;
        __sincosf(0.5f * (a + c), &sh, &ch);
        __sincosf(0.5f * (a - c), &sd, &cd);
        __sincosf(0.5f * bb, &sb, &cb);
        // M00 = cb*e^{-i(a+c)/2}, M01 = sb*(sin d, -cos d)
        sG[tid] = make_float4(cb * ch, -cb * sh, sb * sd, -sb * cd);
    }
    if (tid < 40) {
        const float* srcs[5] = {wq_crx, wk_crx, wc_crx, wc_crx2, wv_crx};
        const float t = srcs[tid >> 3][tid & 7];
        float s_, c_;
        __sincosf(0.5f * t, &s_, &c_);
        sCS[tid] = make_float2(c_, s_);
    }
    __syncthreads();

    const int l16 = tid & 15;
    const int b = blockIdx.x * 16 + (tid >> 4);

    // ---- projections (group-cooperative, W from LDS transposed) -----------
    const float* xt = x_text + (size_t)b * 96;
    const float* xi = x_image + (size_t)b * 96;
    float aq[4] = {0.f, 0.f, 0.f, 0.f}, ak[4] = {0.f, 0.f, 0.f, 0.f};
#pragma unroll
    for (int k = 0; k < 6; k++) {
        const int idx = l16 + 16 * k;
        const float vq = xt[idx], vk = xi[idx];
        const float4 wq = sWT[idx], wk = sWT[96 + idx];
        aq[0] += vq * wq.x; aq[1] += vq * wq.y; aq[2] += vq * wq.z; aq[3] += vq * wq.w;
        ak[0] += vk * wk.x; ak[1] += vk * wk.y; ak[2] += vk * wk.z; ak[3] += vk * wk.w;
    }
    float xq[4], xk[4];
#pragma unroll
    for (int j = 0; j < 4; j++) {
        xq[j] = red16(aq[j]) + b_text[j];
        xk[j] = red16(ak[j]) + b_image[j];
    }

    // ---- 8-qubit score circuit --------------------------------------------
    float2 s[16];
#pragma unroll
    for (int r = 0; r < 16; r++) s[r] = make_float2(0.f, 0.f);
    s[0].x = (l16 == 0) ? 1.f : 0.f;

    {   // q-ring layer1 fused with q embedding (register wires)
        float2 u00, u01;
        fuse_rx(sG[0], xq[0], u00, u01); rgate<8>(s, u00, u01);
        fuse_rx(sG[1], xq[1], u00, u01); rgate<4>(s, u00, u01);
        fuse_rx(sG[2], xq[2], u00, u01); rgate<2>(s, u00, u01);
        fuse_rx(sG[3], xq[3], u00, u01); rgate<1>(s, u00, u01);
    }
    crx_rr<8, 4>(s, sCS[0]); crx_rr<4, 2>(s, sCS[1]);
    crx_rr<2, 1>(s, sCS[2]); crx_rr<1, 8>(s, sCS[3]);
    ixx_rr<12>(s, sCS[4]); ixx_rr<6>(s, sCS[5]);
    ixx_rr<3>(s, sCS[6]);  ixx_rr<9>(s, sCS[7]);
    rgate4<8>(s, sG[4]); rgate4<4>(s, sG[5]);
    rgate4<2>(s, sG[6]); rgate4<1>(s, sG[7]);

    {   // k-ring layer1 fused with k embedding (lane wires)
        float2 u00, u01;
        fuse_rx(sG[8],  xk[0], u00, u01); lgate<8>(s, l16, u00, u01);
        fuse_rx(sG[9],  xk[1], u00, u01); lgate<4>(s, l16, u00, u01);
        fuse_rx(sG[10], xk[2], u00, u01); lgate<2>(s, l16, u00, u01);
        fuse_rx(sG[11], xk[3], u00, u01); lgate<1>(s, l16, u00, u01);
    }
    crx_ll<8, 4>(s, l16, sCS[8]);  crx_ll<4, 2>(s, l16, sCS[9]);
    crx_ll<2, 1>(s, l16, sCS[10]); crx_ll<1, 8>(s, l16, sCS[11]);
    ixx_ll<12>(s, sCS[12]); ixx_ll<6>(s, sCS[13]);
    ixx_ll<3>(s, sCS[14]);  ixx_ll<9>(s, sCS[15]);
    lgate4<8>(s, l16, sG[12]); lgate4<4>(s, l16, sG[13]);
    lgate4<2>(s, l16, sG[14]); lgate4<1>(s, l16, sG[15]);

    // cross CRX (i, i+4) / (i+4, i)
    crx_rl<8, 8>(s, sCS[16]); crx_lr<8, 8>(s, l16, sCS[20]);
    crx_rl<4, 4>(s, sCS[17]); crx_lr<4, 4>(s, l16, sCS[21]);
    crx_rl<2, 2>(s, sCS[18]); crx_lr<2, 2>(s, l16, sCS[22]);
    crx_rl<1, 1>(s, sCS[19]); crx_lr<1, 1>(s, l16, sCS[23]);
    // crx2: (i, (i+1)%4+4) then (i+4, (i+1)%4)
    crx_rl<8, 4>(s, sCS[24]); crx_rl<4, 2>(s, sCS[25]);
    crx_rl<2, 1>(s, sCS[26]); crx_rl<1, 8>(s, sCS[27]);
    crx_lr<8, 4>(s, l16, sCS[28]); crx_lr<4, 2>(s, l16, sCS[29]);
    crx_lr<2, 1>(s, l16, sCS[30]); crx_lr<1, 8>(s, l16, sCS[31]);
    // CNOT (i, i+4) then (i+4, i), interleaved per i
    cnot_rl<8, 8>(s); cnot_lr<8, 8>(s, l16);
    cnot_rl<4, 4>(s); cnot_lr<4, 4>(s, l16);
    cnot_rl<2, 2>(s); cnot_lr<2, 2>(s, l16);
    cnot_rl<1, 1>(s); cnot_lr<1, 1>(s, l16);
    // final rot layer (register wires)
    rgate4<8>(s, sG[16]); rgate4<4>(s, sG[17]);
    rgate4<2>(s, sG[18]); rgate4<1>(s, sG[19]);

    // ---- expectations & amp ----------------------------------------------
    float amp[4];
    {
        float z0, x0, z1, x1, z2, x2, z3, x3;
        measZX<8>(s, z0, x0); measZX<4>(s, z1, x1);
        measZX<2>(s, z2, x2); measZX<1>(s, z3, x3);
        z0 = red16(z0); x0 = red16(x0);
        z1 = red16(z1); x1 = red16(x1);
        z2 = red16(z2); x2 = red16(x2);
        z3 = red16(z3); x3 = red16(x3);
        amp[0] = sqrtf(z0 * z0 + x0 * x0);
        amp[1] = sqrtf(z1 * z1 + x1 * x1);
        amp[2] = sqrtf(z2 * z2 + x2 * x2);
        amp[3] = sqrtf(z3 * z3 + x3 * x3);
    }

    // ---- 4-qubit value circuit (xv = xk) ----------------------------------
    float2 v = make_float2((l16 == 0) ? 1.f : 0.f, 0.f);
    {
        float2 u00, u01;
        fuse_rx(sG[20], xk[0], u00, u01); vgate<8>(v, l16, u00, u01);
        fuse_rx(sG[21], xk[1], u00, u01); vgate<4>(v, l16, u00, u01);
        fuse_rx(sG[22], xk[2], u00, u01); vgate<2>(v, l16, u00, u01);
        fuse_rx(sG[23], xk[3], u00, u01); vgate<1>(v, l16, u00, u01);
    }
    vcrx<8, 4>(v, l16, sCS[32]); vcrx<4, 2>(v, l16, sCS[33]);
    vcrx<2, 1>(v, l16, sCS[34]); vcrx<1, 8>(v, l16, sCS[35]);
    vixx<12>(v, sCS[36]); vixx<6>(v, sCS[37]);
    vixx<3>(v, sCS[38]);  vixx<9>(v, sCS[39]);
    vgate4<8>(v, l16, sG[24]); vgate4<4>(v, l16, sG[25]);
    vgate4<2>(v, l16, sG[26]); vgate4<1>(v, l16, sG[27]);
#pragma unroll
    for (int i = 0; i < 4; i++) {
        const float ang = tanhf(amp[i]) * gates[i];
        float s_, c_;
        __sincosf(0.5f * ang, &s_, &c_);
        if (i == 0) vrx<8>(v, c_, s_);
        if (i == 1) vrx<4>(v, c_, s_);
        if (i == 2) vrx<2>(v, c_, s_);
        if (i == 3) vrx<1>(v, c_, s_);
    }
    vcnot<8, 4>(v, l16); vcnot<4, 2>(v, l16);
    vcnot<2, 1>(v, l16); vcnot<1, 8>(v, l16);

    // ---- value expectations + write ---------------------------------------
    const float n2 = v.x * v.x + v.y * v.y;
    float oz[4], ox[4];
    {
        const float2 p8 = lxor2<8>(v), p4 = lxor2<4>(v),
                     p2 = lxor2<2>(v), p1 = lxor2<1>(v);
        oz[0] = red16((l16 & 8) ? -n2 : n2);
        oz[1] = red16((l16 & 4) ? -n2 : n2);
        oz[2] = red16((l16 & 2) ? -n2 : n2);
        oz[3] = red16((l16 & 1) ? -n2 : n2);
        ox[0] = red16(v.x * p8.x + v.y * p8.y);
        ox[1] = red16(v.x * p4.x + v.y * p4.y);
        ox[2] = red16(v.x * p2.x + v.y * p2.y);
        ox[3] = red16(v.x * p1.x + v.y * p1.y);
    }
    if (l16 == 0) {
        float4* o = (float4*)(out + (size_t)b * 8);
        o[0] = make_float4(oz[0], oz[1], oz[2], oz[3]);
        o[1] = make_float4(ox[0], ox[1], ox[2], ox[3]);
    }
}

extern "C" void kernel_launch(void* const* d_in, const int* in_sizes, int n_in,
                              void* d_out, int out_size, void* d_ws, size_t ws_size,
                              hipStream_t stream) {
    (void)n_in; (void)out_size; (void)d_ws; (void)ws_size;
    const int B = in_sizes[0] / 96;
    const dim3 grid((B + 15) / 16), block(256);
    hipLaunchKernelGGL(qa_kernel, grid, block, 0, stream,
                       (const float*)d_in[0], (const float*)d_in[1],
                       (const float*)d_in[2], (const float*)d_in[3],
                       (const float*)d_in[4], (const float*)d_in[5],
                       (const float*)d_in[6], (const float*)d_in[7],
                       (const float*)d_in[8], (const float*)d_in[9],
                       (const float*)d_in[10], (const float*)d_in[11],
                       (const float*)d_in[12], (const float*)d_in[13],
                       (const float*)d_in[14], (const float*)d_in[15],
                       (float*)d_out, B);
}

// Round 3
// 93.276 us; speedup vs baseline: 1.2358x; 1.0984x over previous
//
#include <hip/hip_runtime.h>
#include <math.h>

#define DEV __device__ __forceinline__

// ---------------------------------------------------------------------------
// Cross-lane xor within 16-lane groups. Masks 1,2,3 -> DPP quad_perm,
// mask 8 -> DPP row_ror:8, else ds_swizzle (bit-mode, stays within 32 lanes).
// ---------------------------------------------------------------------------
template<int M>
DEV float lxor(float x) {
    const int i = __builtin_bit_cast(int, x);
    int r;
    if constexpr (M == 1)      r = __builtin_amdgcn_update_dpp(i, i, 0xB1, 0xF, 0xF, false);
    else if constexpr (M == 2) r = __builtin_amdgcn_update_dpp(i, i, 0x4E, 0xF, 0xF, false);
    else if constexpr (M == 3) r = __builtin_amdgcn_update_dpp(i, i, 0x1B, 0xF, 0xF, false);
    else if constexpr (M == 8) r = __builtin_amdgcn_update_dpp(i, i, 0x128, 0xF, 0xF, false);
    else                       r = __builtin_amdgcn_ds_swizzle(i, (M << 10) | 0x1F);
    return __builtin_bit_cast(float, r);
}
template<int M> DEV float2 lxor2(float2 v) {
    return make_float2(lxor<M>(v.x), lxor<M>(v.y));
}
DEV float red16(float x) {
    x += lxor<8>(x); x += lxor<4>(x); x += lxor<2>(x); x += lxor<1>(x);
    return x;
}

// ---------------------------------------------------------------------------
// Single-amplitude (16-amp state, 1 amp/lane in a 16-lane group) gate helpers.
// Wire w of a 4-qubit register <-> lane-bit mask (8 >> w).
// SU(2): U = [[u00, u01], [-conj(u01), conj(u00)]].
// ---------------------------------------------------------------------------
template<int LM>
DEV void sgate(float2& v, int l16, float2 u00, float2 u01) {
    const bool hi = (l16 & LM) != 0;
    const float e00x = u00.x, e00y = hi ? -u00.y : u00.y;
    const float e01x = hi ? -u01.x : u01.x, e01y = u01.y;
    const float2 p = lxor2<LM>(v);
    v = make_float2(e00x*v.x - e00y*v.y + e01x*p.x - e01y*p.y,
                    e00x*v.y + e00y*v.x + e01x*p.y + e01y*p.x);
}
template<int LM>
DEV void sgate4(float2& v, int l16, float4 g) {
    sgate<LM>(v, l16, make_float2(g.x, g.y), make_float2(g.z, g.w));
}
template<int CL, int LM>
DEV void scrx(float2& v, int l16, float2 cs) {
    const bool hi = (l16 & CL) != 0;
    const float c = hi ? cs.x : 1.f, sn = hi ? cs.y : 0.f;
    const float2 p = lxor2<LM>(v);
    v = make_float2(c*v.x + sn*p.y, c*v.y - sn*p.x);
}
template<int LM2>
DEV void sixx(float2& v, float2 cs) {
    const float2 p = lxor2<LM2>(v);
    v = make_float2(cs.x*v.x + cs.y*p.y, cs.x*v.y - cs.y*p.x);
}
template<int LM>
DEV void srx(float2& v, float c, float sn) {
    const float2 p = lxor2<LM>(v);
    v = make_float2(c*v.x + sn*p.y, c*v.y - sn*p.x);
}
template<int CL, int LM>
DEV void scnot(float2& v, int l16) {
    const float2 p = lxor2<LM>(v);
    const bool hi = (l16 & CL) != 0;
    v = hi ? p : v;
}

// ---------------------------------------------------------------------------
// Full 256-amp state: 16 float2/lane (register bits = wires 0..3, mask 8>>w),
// 16 lanes/element (lane bits = wires 4..7, mask 8>>(w-4)).
// ---------------------------------------------------------------------------
template<int CM, int LM>
DEV void crx_rl(float2 (&s)[16], float2 cs) {   // control reg wire, target lane wire
#pragma unroll
    for (int r = 0; r < 16; r++) {
        if (!(r & CM)) continue;
        const float2 p = lxor2<LM>(s[r]);
        const float2 a = s[r];
        s[r] = make_float2(cs.x*a.x + cs.y*p.y, cs.x*a.y - cs.y*p.x);
    }
}
template<int CL, int TM>
DEV void crx_lr(float2 (&s)[16], int l16, float2 cs) {  // control lane, target reg
    const bool hi = (l16 & CL) != 0;
    const float c = hi ? cs.x : 1.f, sn = hi ? cs.y : 0.f;
#pragma unroll
    for (int r = 0; r < 16; r++) {
        if (r & TM) continue;
        const int r1 = r | TM;
        const float2 a = s[r], b = s[r1];
        s[r]  = make_float2(c*a.x + sn*b.y, c*a.y - sn*b.x);
        s[r1] = make_float2(c*b.x + sn*a.y, c*b.y - sn*a.x);
    }
}
template<int CM, int LM>
DEV void cnot_rl(float2 (&s)[16]) {
#pragma unroll
    for (int r = 0; r < 16; r++) {
        if (r & CM) s[r] = lxor2<LM>(s[r]);
    }
}
template<int CL, int TM>
DEV void cnot_lr(float2 (&s)[16], int l16) {
    const bool hi = (l16 & CL) != 0;
#pragma unroll
    for (int r = 0; r < 16; r++) {
        if (r & TM) continue;
        const int r1 = r | TM;
        const float2 a = s[r], b = s[r1];
        s[r]  = hi ? b : a;
        s[r1] = hi ? a : b;
    }
}

// Heisenberg measurement of A = U^dag P U on register wire RM.
// mz = (az, bz2_re, bz2_im, ax); bx = (bx2_re, bx2_im).
// <A> = sum_pairs a*(n0-n1) + b2_re*d_re - b2_im*d_im, d = conj(s0)*s1.
template<int RM>
DEV void measU(const float2 (&s)[16], const float (&n2)[16],
               float4 mz, float2 bx, float& z, float& x) {
    float zz = 0.f, xx = 0.f;
#pragma unroll
    for (int r = 0; r < 16; r++) {
        if (r & RM) continue;
        const int r1 = r | RM;
        const float nd  = n2[r] - n2[r1];
        const float dre = s[r].x*s[r1].x + s[r].y*s[r1].y;
        const float dim = s[r].x*s[r1].y - s[r].y*s[r1].x;
        zz += mz.x*nd + mz.y*dre - mz.z*dim;
        xx += mz.w*nd + bx.x*dre - bx.y*dim;
    }
    z = zz; x = xx;
}

// Fuse rot-layer SU(2) g with preceding RX(ang): U' = M * RX(ang)
DEV void fuse_rx(float4 g, float ang, float2& u00, float2& u01) {
    float s_, c_;
    __sincosf(0.5f * ang, &s_, &c_);
    u00 = make_float2(g.x*c_ + g.w*s_, g.y*c_ - g.z*s_);
    u01 = make_float2(g.y*s_ + g.z*c_, -g.x*s_ + g.w*c_);
}

// ---------------------------------------------------------------------------
__global__ __launch_bounds__(256, 1) void qa_kernel(
    const float* __restrict__ x_text, const float* __restrict__ x_image,
    const float* __restrict__ W_text, const float* __restrict__ b_text,
    const float* __restrict__ W_image, const float* __restrict__ b_image,
    const float* __restrict__ wq_rot, const float* __restrict__ wq_crx,
    const float* __restrict__ wk_rot, const float* __restrict__ wk_crx,
    const float* __restrict__ wv_rot, const float* __restrict__ wv_crx,
    const float* __restrict__ wc_rot, const float* __restrict__ wc_crx,
    const float* __restrict__ wc_crx2, const float* __restrict__ gates,
    float* __restrict__ out, int B)
{
    // sG fused SU(2): 0-3 qL1, 4-7 qL2, 8-11 kL1, 12-15 kL2, 16-19 final(wc),
    // 20-23 vL1, 24-27 vL2.
    __shared__ float4 sG[28];
    // sCS (cos,sin of t/2): 0-7 wq_crx, 8-15 wk_crx, 16-23 wc_crx,
    // 24-31 wc_crx2, 32-39 wv_crx.
    __shared__ float2 sCS[40];
    __shared__ float4 sWT[192];   // W rows transposed
    __shared__ float4 sMZ[4];     // (az, bz2re, bz2im, ax) per wire
    __shared__ float2 sBX[4];     // (bx2re, bx2im) per wire
    __shared__ __align__(16) float2 sQ[16][18];  // padded: stride 144 B

    const int tid = threadIdx.x;
    if (tid < 192) {
        const float* W = (tid < 96) ? W_text : W_image;
        const int idx = (tid < 96) ? tid : tid - 96;
        sWT[tid] = make_float4(W[idx], W[96 + idx], W[192 + idx], W[288 + idx]);
    }
    if (tid < 28) {
        const float* srcs[7] = {wq_rot, wq_rot + 12, wk_rot, wk_rot + 12,
                                wc_rot, wv_rot, wv_rot + 12};
        const float* p = srcs[tid >> 2] + 3 * (tid & 3);
        const float a = p[0], bb = p[1], c = p[2];
        float sh, ch, sd, cd, sb, cb;
        __sincosf(0.5f * (a + c), &sh, &ch);
        __sincosf(0.5f * (a - c), &sd, &cd);
        __sincosf(0.5f * bb, &sb, &cb);
        const float4 g = make_float4(cb * ch, -cb * sh, sb * sd, -sb * cd);
        sG[tid] = g;
        if (tid >= 16 && tid < 20) {  // Heisenberg ops for the final rot layer
            const int w = tid - 16;
            const float2 u00 = make_float2(g.x, g.y), u01 = make_float2(g.z, g.w);
            const float az = u00.x*u00.x + u00.y*u00.y - u01.x*u01.x - u01.y*u01.y;
            sMZ[w] = make_float4(az,
                                 4.f*(u00.x*u01.x + u00.y*u01.y),
                                 4.f*(u00.x*u01.y - u00.y*u01.x),
                                 -2.f*(u00.x*u01.x - u00.y*u01.y));
            sBX[w] = make_float2(
                2.f*(u00.x*u00.x - u00.y*u00.y - u01.x*u01.x + u01.y*u01.y),
                -4.f*(u00.x*u00.y + u01.x*u01.y));
        }
    }
    if (tid < 40) {
        const float* srcs[5] = {wq_crx, wk_crx, wc_crx, wc_crx2, wv_crx};
        const float t = srcs[tid >> 3][tid & 7];
        float s_, c_;
        __sincosf(0.5f * t, &s_, &c_);
        sCS[tid] = make_float2(c_, s_);
    }
    __syncthreads();

    const int l16 = tid & 15;
    const int elem = tid >> 4;
    const int b = blockIdx.x * 16 + elem;

    // ---- projections -------------------------------------------------------
    const float* xt = x_text + (size_t)b * 96;
    const float* xi = x_image + (size_t)b * 96;
    float aq[4] = {0.f, 0.f, 0.f, 0.f}, ak[4] = {0.f, 0.f, 0.f, 0.f};
#pragma unroll
    for (int kk = 0; kk < 6; kk++) {
        const int idx = l16 + 16 * kk;
        const float vq = xt[idx], vk = xi[idx];
        const float4 wq = sWT[idx], wk = sWT[96 + idx];
        aq[0] += vq * wq.x; aq[1] += vq * wq.y; aq[2] += vq * wq.z; aq[3] += vq * wq.w;
        ak[0] += vk * wk.x; ak[1] += vk * wk.y; ak[2] += vk * wk.z; ak[3] += vk * wk.w;
    }
    float xq[4], xk[4];
#pragma unroll
    for (int j = 0; j < 4; j++) {
        xq[j] = red16(aq[j]) + b_text[j];
        xk[j] = red16(ak[j]) + b_image[j];
    }

    // ---- three independent 16-amp ring sims (q, k, v), interleaved --------
    float2 q  = make_float2((l16 == 0) ? 1.f : 0.f, 0.f);
    float2 k  = q, vv = q;
    {
        float2 u00, u01;
        fuse_rx(sG[0],  xq[0], u00, u01); sgate<8>(q,  l16, u00, u01);
        fuse_rx(sG[8],  xk[0], u00, u01); sgate<8>(k,  l16, u00, u01);
        fuse_rx(sG[20], xk[0], u00, u01); sgate<8>(vv, l16, u00, u01);
        fuse_rx(sG[1],  xq[1], u00, u01); sgate<4>(q,  l16, u00, u01);
        fuse_rx(sG[9],  xk[1], u00, u01); sgate<4>(k,  l16, u00, u01);
        fuse_rx(sG[21], xk[1], u00, u01); sgate<4>(vv, l16, u00, u01);
        fuse_rx(sG[2],  xq[2], u00, u01); sgate<2>(q,  l16, u00, u01);
        fuse_rx(sG[10], xk[2], u00, u01); sgate<2>(k,  l16, u00, u01);
        fuse_rx(sG[22], xk[2], u00, u01); sgate<2>(vv, l16, u00, u01);
        fuse_rx(sG[3],  xq[3], u00, u01); sgate<1>(q,  l16, u00, u01);
        fuse_rx(sG[11], xk[3], u00, u01); sgate<1>(k,  l16, u00, u01);
        fuse_rx(sG[23], xk[3], u00, u01); sgate<1>(vv, l16, u00, u01);
    }
    scrx<8, 4>(q, l16, sCS[0]);  scrx<8, 4>(k, l16, sCS[8]);  scrx<8, 4>(vv, l16, sCS[32]);
    scrx<4, 2>(q, l16, sCS[1]);  scrx<4, 2>(k, l16, sCS[9]);  scrx<4, 2>(vv, l16, sCS[33]);
    scrx<2, 1>(q, l16, sCS[2]);  scrx<2, 1>(k, l16, sCS[10]); scrx<2, 1>(vv, l16, sCS[34]);
    scrx<1, 8>(q, l16, sCS[3]);  scrx<1, 8>(k, l16, sCS[11]); scrx<1, 8>(vv, l16, sCS[35]);
    sixx<12>(q, sCS[4]);  sixx<12>(k, sCS[12]); sixx<12>(vv, sCS[36]);
    sixx<6>(q, sCS[5]);   sixx<6>(k, sCS[13]);  sixx<6>(vv, sCS[37]);
    sixx<3>(q, sCS[6]);   sixx<3>(k, sCS[14]);  sixx<3>(vv, sCS[38]);
    sixx<9>(q, sCS[7]);   sixx<9>(k, sCS[15]);  sixx<9>(vv, sCS[39]);
    sgate4<8>(q, l16, sG[4]);  sgate4<8>(k, l16, sG[12]);  sgate4<8>(vv, l16, sG[24]);
    sgate4<4>(q, l16, sG[5]);  sgate4<4>(k, l16, sG[13]);  sgate4<4>(vv, l16, sG[25]);
    sgate4<2>(q, l16, sG[6]);  sgate4<2>(k, l16, sG[14]);  sgate4<2>(vv, l16, sG[26]);
    sgate4<1>(q, l16, sG[7]);  sgate4<1>(k, l16, sG[15]);  sgate4<1>(vv, l16, sG[27]);

    // ---- outer product |q> (x) |k| -> full 256-amp state -------------------
    // Same-wave LDS round-trip (group-private row) -> no barrier needed.
    sQ[elem][l16] = q;
    const float4* qrow = reinterpret_cast<const float4*>(&sQ[elem][0]);
    float2 s[16];
#pragma unroll
    for (int j = 0; j < 8; j++) {
        const float4 t = qrow[j];
        s[2*j]   = make_float2(t.x*k.x - t.y*k.y, t.x*k.y + t.y*k.x);
        s[2*j+1] = make_float2(t.z*k.x - t.w*k.y, t.z*k.y + t.w*k.x);
    }

    // ---- cross section (entangling) ----------------------------------------
    crx_rl<8, 8>(s, sCS[16]); crx_lr<8, 8>(s, l16, sCS[20]);
    crx_rl<4, 4>(s, sCS[17]); crx_lr<4, 4>(s, l16, sCS[21]);
    crx_rl<2, 2>(s, sCS[18]); crx_lr<2, 2>(s, l16, sCS[22]);
    crx_rl<1, 1>(s, sCS[19]); crx_lr<1, 1>(s, l16, sCS[23]);
    crx_rl<8, 4>(s, sCS[24]); crx_rl<4, 2>(s, sCS[25]);
    crx_rl<2, 1>(s, sCS[26]); crx_rl<1, 8>(s, sCS[27]);
    crx_lr<8, 4>(s, l16, sCS[28]); crx_lr<4, 2>(s, l16, sCS[29]);
    crx_lr<2, 1>(s, l16, sCS[30]); crx_lr<1, 8>(s, l16, sCS[31]);
    cnot_rl<8, 8>(s); cnot_lr<8, 8>(s, l16);
    cnot_rl<4, 4>(s); cnot_lr<4, 4>(s, l16);
    cnot_rl<2, 2>(s); cnot_lr<2, 2>(s, l16);
    cnot_rl<1, 1>(s); cnot_lr<1, 1>(s, l16);

    // ---- Heisenberg measurement (final rot layer folded into observables) --
    float n2[16];
#pragma unroll
    for (int r = 0; r < 16; r++) n2[r] = s[r].x*s[r].x + s[r].y*s[r].y;
    float amp[4];
    {
        float z0, x0, z1, x1, z2, x2, z3, x3;
        measU<8>(s, n2, sMZ[0], sBX[0], z0, x0);
        measU<4>(s, n2, sMZ[1], sBX[1], z1, x1);
        measU<2>(s, n2, sMZ[2], sBX[2], z2, x2);
        measU<1>(s, n2, sMZ[3], sBX[3], z3, x3);
        z0 = red16(z0); x0 = red16(x0);
        z1 = red16(z1); x1 = red16(x1);
        z2 = red16(z2); x2 = red16(x2);
        z3 = red16(z3); x3 = red16(x3);
        amp[0] = sqrtf(z0*z0 + x0*x0);
        amp[1] = sqrtf(z1*z1 + x1*x1);
        amp[2] = sqrtf(z2*z2 + x2*x2);
        amp[3] = sqrtf(z3*z3 + x3*x3);
    }

    // ---- value circuit tail ------------------------------------------------
#pragma unroll
    for (int i = 0; i < 4; i++) {
        // tanh via exp (amp >= 0, no overflow concern)
        const float e = __expf(2.f * amp[i]);
        const float th = 1.f - 2.f / (e + 1.f);
        const float ang = th * gates[i];
        float s_, c_;
        __sincosf(0.5f * ang, &s_, &c_);
        if (i == 0) srx<8>(vv, c_, s_);
        if (i == 1) srx<4>(vv, c_, s_);
        if (i == 2) srx<2>(vv, c_, s_);
        if (i == 3) srx<1>(vv, c_, s_);
    }
    scnot<8, 4>(vv, l16); scnot<4, 2>(vv, l16);
    scnot<2, 1>(vv, l16); scnot<1, 8>(vv, l16);

    // ---- value expectations + write ---------------------------------------
    const float vn2 = vv.x*vv.x + vv.y*vv.y;
    float oz[4], ox[4];
    {
        const float2 p8 = lxor2<8>(vv), p4 = lxor2<4>(vv),
                     p2 = lxor2<2>(vv), p1 = lxor2<1>(vv);
        oz[0] = red16((l16 & 8) ? -vn2 : vn2);
        oz[1] = red16((l16 & 4) ? -vn2 : vn2);
        oz[2] = red16((l16 & 2) ? -vn2 : vn2);
        oz[3] = red16((l16 & 1) ? -vn2 : vn2);
        ox[0] = red16(vv.x*p8.x + vv.y*p8.y);
        ox[1] = red16(vv.x*p4.x + vv.y*p4.y);
        ox[2] = red16(vv.x*p2.x + vv.y*p2.y);
        ox[3] = red16(vv.x*p1.x + vv.y*p1.y);
    }
    if (l16 == 0) {
        float4* o = (float4*)(out + (size_t)b * 8);
        o[0] = make_float4(oz[0], oz[1], oz[2], oz[3]);
        o[1] = make_float4(ox[0], ox[1], ox[2], ox[3]);
    }
}

extern "C" void kernel_launch(void* const* d_in, const int* in_sizes, int n_in,
                              void* d_out, int out_size, void* d_ws, size_t ws_size,
                              hipStream_t stream) {
    (void)n_in; (void)out_size; (void)d_ws; (void)ws_size;
    const int B = in_sizes[0] / 96;
    const dim3 grid((B + 15) / 16), block(256);
    hipLaunchKernelGGL(qa_kernel, grid, block, 0, stream,
                       (const float*)d_in[0], (const float*)d_in[1],
                       (const float*)d_in[2], (const float*)d_in[3],
                       (const float*)d_in[4], (const float*)d_in[5],
                       (const float*)d_in[6], (const float*)d_in[7],
                       (const float*)d_in[8], (const float*)d_in[9],
                       (const float*)d_in[10], (const float*)d_in[11],
                       (const float*)d_in[12], (const float*)d_in[13],
                       (const float*)d_in[14], (const float*)d_in[15],
                       (float*)d_out, B);
}

// Round 4
// 91.818 us; speedup vs baseline: 1.2554x; 1.0159x over previous
//
#include <hip/hip_runtime.h>
#include <math.h>

#define DEV __device__ __forceinline__

// ---------------------------------------------------------------------------
// Cross-lane xor within 32-lane groups. Masks 1,2,3 -> DPP quad_perm,
// mask 8 -> DPP row_ror:8 (16-lane row), others (4,6,9,12,16) -> ds_swizzle
// bit-mode (xor<=31 stays within 32-lane groups).
// ---------------------------------------------------------------------------
template<int M>
DEV float lxor(float x) {
    const int i = __builtin_bit_cast(int, x);
    int r;
    if constexpr (M == 1)      r = __builtin_amdgcn_update_dpp(i, i, 0xB1, 0xF, 0xF, false);
    else if constexpr (M == 2) r = __builtin_amdgcn_update_dpp(i, i, 0x4E, 0xF, 0xF, false);
    else if constexpr (M == 3) r = __builtin_amdgcn_update_dpp(i, i, 0x1B, 0xF, 0xF, false);
    else if constexpr (M == 8) r = __builtin_amdgcn_update_dpp(i, i, 0x128, 0xF, 0xF, false);
    else                       r = __builtin_amdgcn_ds_swizzle(i, (M << 10) | 0x1F);
    return __builtin_bit_cast(float, r);
}
template<int M> DEV float2 lxor2(float2 v) {
    return make_float2(lxor<M>(v.x), lxor<M>(v.y));
}
DEV float red16(float x) {
    x += lxor<8>(x); x += lxor<4>(x); x += lxor<2>(x); x += lxor<1>(x);
    return x;
}
DEV float red32(float x) {
    x += lxor<16>(x);
    return red16(x);
}

// ---------------------------------------------------------------------------
// 16-amp ring-sim helpers: 1 amp/lane within a 16-lane half; wire w <-> mask 8>>w.
// SU(2): U = [[u00, u01], [-conj(u01), conj(u00)]].
// ---------------------------------------------------------------------------
template<int LM>
DEV void sgate(float2& v, int l16, float2 u00, float2 u01) {
    const bool hi = (l16 & LM) != 0;
    const float e00x = u00.x, e00y = hi ? -u00.y : u00.y;
    const float e01x = hi ? -u01.x : u01.x, e01y = u01.y;
    const float2 p = lxor2<LM>(v);
    v = make_float2(e00x*v.x - e00y*v.y + e01x*p.x - e01y*p.y,
                    e00x*v.y + e00y*v.x + e01x*p.y + e01y*p.x);
}
template<int LM>
DEV void sgate4(float2& v, int l16, float4 g) {
    sgate<LM>(v, l16, make_float2(g.x, g.y), make_float2(g.z, g.w));
}
template<int CL, int LM>
DEV void scrx(float2& v, int l16, float2 cs) {
    const bool hi = (l16 & CL) != 0;
    const float c = hi ? cs.x : 1.f, sn = hi ? cs.y : 0.f;
    const float2 p = lxor2<LM>(v);
    v = make_float2(c*v.x + sn*p.y, c*v.y - sn*p.x);
}
template<int LM2>
DEV void sixx(float2& v, float2 cs) {
    const float2 p = lxor2<LM2>(v);
    v = make_float2(cs.x*v.x + cs.y*p.y, cs.x*v.y - cs.y*p.x);
}
template<int LM>
DEV void srx(float2& v, float c, float sn) {
    const float2 p = lxor2<LM>(v);
    v = make_float2(c*v.x + sn*p.y, c*v.y - sn*p.x);
}
template<int CL, int LM>
DEV void scnot(float2& v, int l16) {
    const float2 p = lxor2<LM>(v);
    const bool hi = (l16 & CL) != 0;
    v = hi ? p : v;
}

// ---------------------------------------------------------------------------
// Full 256-amp state: 8 float2/lane, 32 lanes/element.
// Wire map: w0 -> lane mask 16; w1,w2,w3 -> reg masks 4,2,1;
//           w4..w7 -> lane masks 8,4,2,1.
// ---------------------------------------------------------------------------
template<int CM, int LM>
DEV void fcrx_rl(float2 (&s)[8], float2 cs) {   // ctrl reg, tgt lane
#pragma unroll
    for (int r = 0; r < 8; r++) {
        if (!(r & CM)) continue;
        const float2 p = lxor2<LM>(s[r]);
        const float2 a = s[r];
        s[r] = make_float2(cs.x*a.x + cs.y*p.y, cs.x*a.y - cs.y*p.x);
    }
}
template<int CL, int RM>
DEV void fcrx_lr(float2 (&s)[8], int l32, float2 cs) {  // ctrl lane, tgt reg
    const bool hi = (l32 & CL) != 0;
    const float c = hi ? cs.x : 1.f, sn = hi ? cs.y : 0.f;
#pragma unroll
    for (int r = 0; r < 8; r++) {
        if (r & RM) continue;
        const int r1 = r | RM;
        const float2 a = s[r], b = s[r1];
        s[r]  = make_float2(c*a.x + sn*b.y, c*a.y - sn*b.x);
        s[r1] = make_float2(c*b.x + sn*a.y, c*b.y - sn*a.x);
    }
}
template<int CL, int LM>
DEV void fcrx_ll(float2 (&s)[8], int l32, float2 cs) {  // ctrl lane, tgt lane
    const bool hi = (l32 & CL) != 0;
    const float c = hi ? cs.x : 1.f, sn = hi ? cs.y : 0.f;
#pragma unroll
    for (int r = 0; r < 8; r++) {
        const float2 p = lxor2<LM>(s[r]);
        const float2 a = s[r];
        s[r] = make_float2(c*a.x + sn*p.y, c*a.y - sn*p.x);
    }
}
template<int CM, int LM>
DEV void fcnot_rl(float2 (&s)[8]) {
#pragma unroll
    for (int r = 0; r < 8; r++)
        if (r & CM) s[r] = lxor2<LM>(s[r]);
}
template<int CL, int RM>
DEV void fcnot_lr(float2 (&s)[8], int l32) {
    const bool hi = (l32 & CL) != 0;
#pragma unroll
    for (int r = 0; r < 8; r++) {
        if (r & RM) continue;
        const int r1 = r | RM;
        const float2 a = s[r], b = s[r1];
        s[r]  = hi ? b : a;
        s[r1] = hi ? a : b;
    }
}
template<int CL, int LM>
DEV void fcnot_ll(float2 (&s)[8], int l32) {
    const bool hi = (l32 & CL) != 0;
#pragma unroll
    for (int r = 0; r < 8; r++) {
        const float2 p = lxor2<LM>(s[r]);
        s[r] = hi ? p : s[r];
    }
}

// Heisenberg measurement of A = U^dag P U on reg wire RM.
// mz = (az, bz2_re, bz2_im, ax); bx = (bx2_re, bx2_im).
template<int RM>
DEV void measR(const float2 (&s)[8], const float (&n2)[8],
               float4 mz, float2 bx, float& z, float& x) {
    float zz = 0.f, xx = 0.f;
#pragma unroll
    for (int r = 0; r < 8; r++) {
        if (r & RM) continue;
        const int r1 = r | RM;
        const float nd  = n2[r] - n2[r1];
        const float dre = s[r].x*s[r1].x + s[r].y*s[r1].y;
        const float dim = s[r].x*s[r1].y - s[r].y*s[r1].x;
        zz += mz.x*nd + mz.y*dre - mz.z*dim;
        xx += mz.w*nd + bx.x*dre - bx.y*dim;
    }
    z = zz; x = xx;
}
// Same for the lane-16 wire (w0). Each lane contributes half of each pair term;
// t = conj(s_l)*s_{l^16}: Re symmetric, Im antisymmetric -> f*t.im is pair-dim
// on both sides.
DEV void measL16(const float2 (&s)[8], const float (&n2)[8], int l32,
                 float4 mz, float2 bx, float& z, float& x) {
    const float f = (l32 & 16) ? -1.f : 1.f;
    float zz = 0.f, xx = 0.f;
#pragma unroll
    for (int r = 0; r < 8; r++) {
        const float2 p = lxor2<16>(s[r]);
        const float tre = s[r].x*p.x + s[r].y*p.y;
        const float ftim = f * (s[r].x*p.y - s[r].y*p.x);
        const float fn = f * n2[r];
        zz += mz.x*fn + 0.5f*(mz.y*tre - mz.z*ftim);
        xx += mz.w*fn + 0.5f*(bx.x*tre - bx.y*ftim);
    }
    z = zz; x = xx;
}

// Fuse rot-layer SU(2) g with preceding RX(ang): U' = M * RX(ang)
DEV void fuse_rx(float4 g, float ang, float2& u00, float2& u01) {
    float s_, c_;
    __sincosf(0.5f * ang, &s_, &c_);
    u00 = make_float2(g.x*c_ + g.w*s_, g.y*c_ - g.z*s_);
    u01 = make_float2(g.y*s_ + g.z*c_, -g.x*s_ + g.w*c_);
}

// ---------------------------------------------------------------------------
__global__ __launch_bounds__(256, 2) void qa_kernel(
    const float* __restrict__ x_text, const float* __restrict__ x_image,
    const float* __restrict__ W_text, const float* __restrict__ b_text,
    const float* __restrict__ W_image, const float* __restrict__ b_image,
    const float* __restrict__ wq_rot, const float* __restrict__ wq_crx,
    const float* __restrict__ wk_rot, const float* __restrict__ wk_crx,
    const float* __restrict__ wv_rot, const float* __restrict__ wv_crx,
    const float* __restrict__ wc_rot, const float* __restrict__ wc_crx,
    const float* __restrict__ wc_crx2, const float* __restrict__ gates,
    float* __restrict__ out, int B)
{
    // sG fused SU(2): 0-3 qL1, 4-7 qL2, 8-11 kL1, 12-15 kL2, 16-19 final(wc),
    // 20-23 vL1, 24-27 vL2.
    __shared__ float4 sG[28];
    // sCS (cos,sin of t/2): 0-7 wq_crx, 8-15 wk_crx, 16-23 wc_crx,
    // 24-31 wc_crx2, 32-39 wv_crx.
    __shared__ float2 sCS[40];
    __shared__ float4 sWT[192];   // W rows transposed
    __shared__ float4 sMZ[4];     // (az, bz2re, bz2im, ax) per measured wire
    __shared__ float2 sBX[4];     // (bx2re, bx2im)
    __shared__ __align__(16) float2 sQK[8][32];  // per element: q[0..15], k[16..31]

    const int tid = threadIdx.x;
    if (tid < 192) {
        const float* W = (tid < 96) ? W_text : W_image;
        const int idx = (tid < 96) ? tid : tid - 96;
        sWT[tid] = make_float4(W[idx], W[96 + idx], W[192 + idx], W[288 + idx]);
    }
    if (tid < 28) {
        const float* srcs[7] = {wq_rot, wq_rot + 12, wk_rot, wk_rot + 12,
                                wc_rot, wv_rot, wv_rot + 12};
        const float* p = srcs[tid >> 2] + 3 * (tid & 3);
        const float a = p[0], bb = p[1], c = p[2];
        float sh, ch, sd, cd, sb, cb;
        __sincosf(0.5f * (a + c), &sh, &ch);
        __sincosf(0.5f * (a - c), &sd, &cd);
        __sincosf(0.5f * bb, &sb, &cb);
        const float4 g = make_float4(cb * ch, -cb * sh, sb * sd, -sb * cd);
        sG[tid] = g;
        if (tid >= 16 && tid < 20) {  // Heisenberg ops for the final rot layer
            const int w = tid - 16;
            const float2 u00 = make_float2(g.x, g.y), u01 = make_float2(g.z, g.w);
            const float az = u00.x*u00.x + u00.y*u00.y - u01.x*u01.x - u01.y*u01.y;
            sMZ[w] = make_float4(az,
                                 4.f*(u00.x*u01.x + u00.y*u01.y),
                                 4.f*(u00.x*u01.y - u00.y*u01.x),
                                 -2.f*(u00.x*u01.x - u00.y*u01.y));
            sBX[w] = make_float2(
                2.f*(u00.x*u00.x - u00.y*u00.y - u01.x*u01.x + u01.y*u01.y),
                -4.f*(u00.x*u00.y + u01.x*u01.y));
        }
    }
    if (tid < 40) {
        const float* srcs[5] = {wq_crx, wk_crx, wc_crx, wc_crx2, wv_crx};
        const float t = srcs[tid >> 3][tid & 7];
        float s_, c_;
        __sincosf(0.5f * t, &s_, &c_);
        sCS[tid] = make_float2(c_, s_);
    }
    __syncthreads();

    const int l32 = tid & 31;
    const int l16 = tid & 15;
    const int hi = (l32 >> 4) & 1;   // 0: q-half, 1: k-half
    const int elem = tid >> 5;
    const int b = blockIdx.x * 8 + elem;

    // ---- projections: both xq and xk in all lanes (v-stream needs xk) ------
    const float* xt = x_text + (size_t)b * 96;
    const float* xi = x_image + (size_t)b * 96;
    float aq[4] = {0.f, 0.f, 0.f, 0.f}, ak[4] = {0.f, 0.f, 0.f, 0.f};
#pragma unroll
    for (int kk = 0; kk < 3; kk++) {
        const int idx = l32 + 32 * kk;
        const float vq = xt[idx], vk = xi[idx];
        const float4 wq = sWT[idx], wk = sWT[96 + idx];
        aq[0] += vq * wq.x; aq[1] += vq * wq.y; aq[2] += vq * wq.z; aq[3] += vq * wq.w;
        ak[0] += vk * wk.x; ak[1] += vk * wk.y; ak[2] += vk * wk.z; ak[3] += vk * wk.w;
    }
    float xq[4], xk[4];
#pragma unroll
    for (int j = 0; j < 4; j++) {
        xq[j] = red32(aq[j]) + b_text[j];
        xk[j] = red32(ak[j]) + b_image[j];
    }

    // ---- ring sims: stream A = q (half0) | k (half1); stream B = v --------
    const float4* gA = sG + (hi ? 8 : 0);
    const float2* cA = sCS + (hi ? 8 : 0);
    float2 A = make_float2((l16 == 0) ? 1.f : 0.f, 0.f);
    float2 V = A;
    {
        float2 u00, u01;
        fuse_rx(gA[0], hi ? xk[0] : xq[0], u00, u01); sgate<8>(A, l16, u00, u01);
        fuse_rx(sG[20], xk[0], u00, u01);             sgate<8>(V, l16, u00, u01);
        fuse_rx(gA[1], hi ? xk[1] : xq[1], u00, u01); sgate<4>(A, l16, u00, u01);
        fuse_rx(sG[21], xk[1], u00, u01);             sgate<4>(V, l16, u00, u01);
        fuse_rx(gA[2], hi ? xk[2] : xq[2], u00, u01); sgate<2>(A, l16, u00, u01);
        fuse_rx(sG[22], xk[2], u00, u01);             sgate<2>(V, l16, u00, u01);
        fuse_rx(gA[3], hi ? xk[3] : xq[3], u00, u01); sgate<1>(A, l16, u00, u01);
        fuse_rx(sG[23], xk[3], u00, u01);             sgate<1>(V, l16, u00, u01);
    }
    scrx<8, 4>(A, l16, cA[0]);  scrx<8, 4>(V, l16, sCS[32]);
    scrx<4, 2>(A, l16, cA[1]);  scrx<4, 2>(V, l16, sCS[33]);
    scrx<2, 1>(A, l16, cA[2]);  scrx<2, 1>(V, l16, sCS[34]);
    scrx<1, 8>(A, l16, cA[3]);  scrx<1, 8>(V, l16, sCS[35]);
    sixx<12>(A, cA[4]);  sixx<12>(V, sCS[36]);
    sixx<6>(A, cA[5]);   sixx<6>(V, sCS[37]);
    sixx<3>(A, cA[6]);   sixx<3>(V, sCS[38]);
    sixx<9>(A, cA[7]);   sixx<9>(V, sCS[39]);
    sgate4<8>(A, l16, gA[4]);  sgate4<8>(V, l16, sG[24]);
    sgate4<4>(A, l16, gA[5]);  sgate4<4>(V, l16, sG[25]);
    sgate4<2>(A, l16, gA[6]);  sgate4<2>(V, l16, sG[26]);
    sgate4<1>(A, l16, gA[7]);  sgate4<1>(V, l16, sG[27]);

    // ---- outer product |q> (x) |k> -> 8 regs/lane --------------------------
    // Same-wave LDS round trip (element spans lanes of one wave).
    sQK[elem][(hi << 4) | l16] = A;
    asm volatile("" ::: "memory");  // keep write before reads
    const float2 kk2 = sQK[elem][16 + l16];
    const float4* qrow = reinterpret_cast<const float4*>(&sQK[elem][hi << 3]);
    float2 s[8];
#pragma unroll
    for (int j = 0; j < 4; j++) {
        const float4 t = qrow[j];
        s[2*j]   = make_float2(t.x*kk2.x - t.y*kk2.y, t.x*kk2.y + t.y*kk2.x);
        s[2*j+1] = make_float2(t.z*kk2.x - t.w*kk2.y, t.z*kk2.y + t.w*kk2.x);
    }

    // ---- cross section (wire map: w0=L16, w1-3=R4/2/1, w4-7=L8/4/2/1) -----
    fcrx_ll<16, 8>(s, l32, sCS[16]); fcrx_ll<8, 16>(s, l32, sCS[20]);
    fcrx_rl<4, 4>(s, sCS[17]);       fcrx_lr<4, 4>(s, l32, sCS[21]);
    fcrx_rl<2, 2>(s, sCS[18]);       fcrx_lr<2, 2>(s, l32, sCS[22]);
    fcrx_rl<1, 1>(s, sCS[19]);       fcrx_lr<1, 1>(s, l32, sCS[23]);
    fcrx_ll<16, 4>(s, l32, sCS[24]);
    fcrx_rl<4, 2>(s, sCS[25]);
    fcrx_rl<2, 1>(s, sCS[26]);
    fcrx_rl<1, 8>(s, sCS[27]);
    fcrx_lr<8, 4>(s, l32, sCS[28]);
    fcrx_lr<4, 2>(s, l32, sCS[29]);
    fcrx_lr<2, 1>(s, l32, sCS[30]);
    fcrx_ll<1, 16>(s, l32, sCS[31]);
    fcnot_ll<16, 8>(s, l32); fcnot_ll<8, 16>(s, l32);
    fcnot_rl<4, 4>(s);       fcnot_lr<4, 4>(s, l32);
    fcnot_rl<2, 2>(s);       fcnot_lr<2, 2>(s, l32);
    fcnot_rl<1, 1>(s);       fcnot_lr<1, 1>(s, l32);

    // ---- Heisenberg measurement -------------------------------------------
    float n2[8];
#pragma unroll
    for (int r = 0; r < 8; r++) n2[r] = s[r].x*s[r].x + s[r].y*s[r].y;
    float amp[4];
    {
        float z0, x0, z1, x1, z2, x2, z3, x3;
        measL16(s, n2, l32, sMZ[0], sBX[0], z0, x0);
        measR<4>(s, n2, sMZ[1], sBX[1], z1, x1);
        measR<2>(s, n2, sMZ[2], sBX[2], z2, x2);
        measR<1>(s, n2, sMZ[3], sBX[3], z3, x3);
        z0 = red32(z0); x0 = red32(x0);
        z1 = red32(z1); x1 = red32(x1);
        z2 = red32(z2); x2 = red32(x2);
        z3 = red32(z3); x3 = red32(x3);
        amp[0] = sqrtf(z0*z0 + x0*x0);
        amp[1] = sqrtf(z1*z1 + x1*x1);
        amp[2] = sqrtf(z2*z2 + x2*x2);
        amp[3] = sqrtf(z3*z3 + x3*x3);
    }

    // ---- value circuit tail ------------------------------------------------
#pragma unroll
    for (int i = 0; i < 4; i++) {
        const float e = __expf(2.f * amp[i]);
        const float th = 1.f - 2.f / (e + 1.f);
        const float ang = th * gates[i];
        float s_, c_;
        __sincosf(0.5f * ang, &s_, &c_);
        if (i == 0) srx<8>(V, c_, s_);
        if (i == 1) srx<4>(V, c_, s_);
        if (i == 2) srx<2>(V, c_, s_);
        if (i == 3) srx<1>(V, c_, s_);
    }
    scnot<8, 4>(V, l16); scnot<4, 2>(V, l16);
    scnot<2, 1>(V, l16); scnot<1, 8>(V, l16);

    // ---- value expectations + write (V replicated across halves) ----------
    const float vn2 = V.x*V.x + V.y*V.y;
    float oz[4], ox[4];
    {
        const float2 p8 = lxor2<8>(V), p4 = lxor2<4>(V),
                     p2 = lxor2<2>(V), p1 = lxor2<1>(V);
        oz[0] = red16((l16 & 8) ? -vn2 : vn2);
        oz[1] = red16((l16 & 4) ? -vn2 : vn2);
        oz[2] = red16((l16 & 2) ? -vn2 : vn2);
        oz[3] = red16((l16 & 1) ? -vn2 : vn2);
        ox[0] = red16(V.x*p8.x + V.y*p8.y);
        ox[1] = red16(V.x*p4.x + V.y*p4.y);
        ox[2] = red16(V.x*p2.x + V.y*p2.y);
        ox[3] = red16(V.x*p1.x + V.y*p1.y);
    }
    if (l32 == 0) {
        float4* o = (float4*)(out + (size_t)b * 8);
        o[0] = make_float4(oz[0], oz[1], oz[2], oz[3]);
        o[1] = make_float4(ox[0], ox[1], ox[2], ox[3]);
    }
}

extern "C" void kernel_launch(void* const* d_in, const int* in_sizes, int n_in,
                              void* d_out, int out_size, void* d_ws, size_t ws_size,
                              hipStream_t stream) {
    (void)n_in; (void)out_size; (void)d_ws; (void)ws_size;
    const int B = in_sizes[0] / 96;
    const dim3 grid((B + 7) / 8), block(256);
    hipLaunchKernelGGL(qa_kernel, grid, block, 0, stream,
                       (const float*)d_in[0], (const float*)d_in[1],
                       (const float*)d_in[2], (const float*)d_in[3],
                       (const float*)d_in[4], (const float*)d_in[5],
                       (const float*)d_in[6], (const float*)d_in[7],
                       (const float*)d_in[8], (const float*)d_in[9],
                       (const float*)d_in[10], (const float*)d_in[11],
                       (const float*)d_in[12], (const float*)d_in[13],
                       (const float*)d_in[14], (const float*)d_in[15],
                       (float*)d_out, B);
}